// Round 9
// baseline (147.308 us; speedup 1.0000x reference)
//
#include <hip/hip_runtime.h>
#include <math.h>

// ---------------- problem constants ----------------
#define SRATE   44100
#define T_IN    441000
#define BATCH   8
#define NB      3
#define NSEQ    (NB*BATCH)        // 24
#define TB_OUT  160000
#define NEW_R   160
#define ORIG_R  441
#define KW      475               // sinc taps
#define KP      480               // K padded to 15*32 for MFMA
#define WIDTH   17
#define NFRAMES 1000

// IIR chunking: 441000 = 6125 * 72 ; warmup 104 (band-2 pole 0.9357^104 = 1.0e-3 residual,
// ~2e-4 at output after 7.2kHz lowpass -- invisible at the 0.0039 bf16 comparison floor).
// Span 176 = 44 quads = exactly 11 ring-4 iterations. 147K threads = 9 waves/CU.
#define LCHUNK  72
#define NCHUNK  6125
#define WARM    104

// workspace layout
#define KTH_OFF 0                 // frag-major bf16-hi table: 160*480 ushort = 153.6 KB
#define KTL_OFF (256u<<10)        // bf16-lo table
#define XLP_OFF (1u<<20)          // xlp f32: 24*441000*4 = 42.3 MB

typedef __attribute__((ext_vector_type(4))) float floatx4;
typedef __attribute__((ext_vector_type(8))) short short8;

// bf16 helpers (RNE) — proven R7
__device__ inline unsigned short f2bf(float f) {
    union { float f; unsigned u; } v; v.f = f;
    unsigned u = v.u, r = (u >> 16) & 0xffffu, rem = u & 0xffffu;
    if (rem > 0x8000u || (rem == 0x8000u && (r & 1u))) r++;
    return (unsigned short)r;
}
__device__ inline float bf2f(unsigned short h) {
    union { unsigned u; float f; } v; v.u = ((unsigned)h) << 16; return v.f;
}

// frag-major flat index (proven R8): ktT[p][k], p = pblk*16+n, k = ks*32+qd*8+j
// -> flat = pblk*7680 + ks*512 + (qd*16+n)*8 + j  (wave load = contiguous 1KB)
__device__ inline int fragB(int p, int k) {
    int pblk = p >> 4, n = p & 15;
    int ks = k >> 5, qd = (k >> 3) & 3, j = k & 7;
    return pblk * 7680 + ks * 512 + (qd * 16 + n) * 8 + j;
}

// ---------------- sinc table -> frag-major bf16-split (math proven R7/R8) ----------------
__global__ void kt_init_kernel(unsigned short* __restrict__ kth,
                               unsigned short* __restrict__ ktl) {
    int idx = blockIdx.x * blockDim.x + threadIdx.x;
    if (idx >= NEW_R * KP) return;
    int p = idx / KP, k = idx - p * KP;
    float v = 0.f;
    if (k < KW) {
        double t = (double)(k - WIDTH) * (158.4 / 441.0) - (double)p * 0.99;
        t = fmin(6.0, fmax(-6.0, t));
        float wc = __builtin_amdgcn_cosf((float)(t * (1.0 / 24.0)));
        double n = rint(t);
        float r2 = (float)((t - n) * 0.5);
        float sp = __builtin_amdgcn_sinf(r2 - floorf(r2));
        if (((long long)n) & 1) sp = -sp;
        float tp = (float)(t * M_PI);
        float snc = (t == 0.0) ? 1.f : sp / tp;
        v = snc * wc * wc * 0.3591836734693878f;
    }
    unsigned short h = f2bf(v);
    int flat = fragB(p, k);
    kth[flat] = h;
    ktl[flat] = f2bf(v - bf2f(h));
}

// ---------------- fused bandpass -> clip -> cos mix -> lowpass -> clip scan (f32) ----
// Heterodyne = XLA-f32 arithmetic (validated R5-R8 at bf16 floor).
struct ScanParams {
    float b0[NB], a1[NB], a2[NB], w[NB];
    float lb0, lb1, lb2, la1, la2;
};

__global__ __launch_bounds__(128) void scan_kernel(const float* __restrict__ x,
                                                   float* __restrict__ xlp,
                                                   ScanParams P) {
    int id = blockIdx.x * blockDim.x + threadIdx.x;
    if (id >= NSEQ * NCHUNK) return;
    int seq   = id / NCHUNK;
    int chunk = id - seq * NCHUNK;
    int band  = seq / BATCH;
    int batch = seq - band * BATCH;

    float b0f = (band == 0) ? P.b0[0] : (band == 1) ? P.b0[1] : P.b0[2];
    float a1f = (band == 0) ? P.a1[0] : (band == 1) ? P.a1[1] : P.a1[2];
    float a2f = (band == 0) ? P.a2[0] : (band == 1) ? P.a2[1] : P.a2[2];
    float wf  = (band == 0) ? P.w[0]  : (band == 1) ? P.w[1]  : P.w[2];
    float b2f = -b0f;
    float lb0 = P.lb0, lb1 = P.lb1, lb2 = P.lb2, la1 = P.la1, la2 = P.la2;

    const float*  xr   = x + batch * T_IN;
    float*        orow = xlp + seq * T_IN;
    const float4* xr4  = (const float4*)xr;

    int t0 = chunk * LCHUNK;          // multiple of 4
    int s0 = t0 - WARM; if (s0 < 0) s0 = 0;
    int e  = t0 + LCHUNK;
    int nq = (e - s0) >> 2;           // 44 (chunk 0: 18)

    float bx1 = 0.f, bx2 = 0.f, by1 = 0.f, by2 = 0.f;
    float mx1 = 0.f, mx2 = 0.f, mz1 = 0.f, mz2 = 0.f;

    const float invsr  = 1.0f / 44100.0f;
    const float INV2PI = 0.15915494309189535f;
    const float PI2_A  = 6.28318548202514648f;
    const float PI2_B  = -1.7484556000744487e-7f;

    const float4 zero = make_float4(0.f, 0.f, 0.f, 0.f);
    const float4* pp = xr4 + (s0 >> 2);
    float4 c0 = pp[0];
    float4 c1 = (1 < nq) ? pp[1] : zero;
    float4 c2 = (2 < nq) ? pp[2] : zero;
    float4 c3 = (3 < nq) ? pp[3] : zero;

    for (int iq = 0; iq < nq; iq += 4) {
        float4 n0 = (iq + 4 < nq) ? pp[iq + 4] : zero;
        float4 n1 = (iq + 5 < nq) ? pp[iq + 5] : zero;
        float4 n2 = (iq + 6 < nq) ? pp[iq + 6] : zero;
        float4 n3 = (iq + 7 < nq) ? pp[iq + 7] : zero;

#define STEP(XT, TI, OUT) {                                                   \
        float y  = b0f*(XT) + b2f*bx2 - a1f*by1 - a2f*by2;                    \
        bx2 = bx1; bx1 = (XT); by2 = by1; by1 = y;                            \
        float cy = fminf(fmaxf(y, -1.f), 1.f);                                \
        float tf = (float)(TI) * invsr;                                       \
        float X  = wf * tf;                                                   \
        float kk = __builtin_rintf(X * INV2PI);                               \
        float r  = fmaf(-kk, PI2_A, X);                                       \
        r        = fmaf(-kk, PI2_B, r);                                       \
        float cv = __builtin_amdgcn_cosf(r * INV2PI);                         \
        float m  = cy * cv;                                                   \
        float z  = lb0*m + lb1*mx1 + lb2*mx2 - la1*mz1 - la2*mz2;             \
        mx2 = mx1; mx1 = m; mz2 = mz1; mz1 = z;                               \
        OUT = fminf(fmaxf(z, -1.f), 1.f); }

#define QUAD(CV, QI) {                                                        \
        int s = s0 + ((iq + QI) << 2);                                        \
        float o0, o1, o2, o3;                                                 \
        STEP(CV.x, s,     o0)                                                 \
        STEP(CV.y, s + 1, o1)                                                 \
        STEP(CV.z, s + 2, o2)                                                 \
        STEP(CV.w, s + 3, o3)                                                 \
        if (s >= t0 && s < e)                                                 \
            ((float4*)orow)[s >> 2] = make_float4(o0, o1, o2, o3); }

        QUAD(c0, 0)
        QUAD(c1, 1)
        QUAD(c2, 2)
        QUAD(c3, 3)
#undef QUAD
#undef STEP
        c0 = n0; c1 = n1; c2 = n2; c3 = n3;
    }
}

// ---------------- MFMA resample (proven R8): out[f,p] = sum_k x[f*441+k-17]*kt[k][p] ----
#define MT2   32      // 32 blocks per sequence x 32 frames = 1024 >= 1000

__global__ __launch_bounds__(320) void resample_mfma(const float* __restrict__ xlp,
                                                     const unsigned short* __restrict__ kth,
                                                     const unsigned short* __restrict__ ktl,
                                                     float* __restrict__ out) {
    __shared__ unsigned short Ah[2][7680];
    __shared__ unsigned short Al[2][7680];

    int bid = blockIdx.x;
    int seq = bid / MT2;
    int mt  = bid - seq * MT2;
    int band  = seq / BATCH;
    int batch = seq - band * BATCH;
    int f0 = mt * 32;
    const float* xr = xlp + seq * T_IN;

    for (int i = threadIdx.x; i < 32 * 120; i += 320) {
        int r  = i / 120;
        int q  = i - r * 120;
        int c  = q * 4;
        int fr = f0 + r;
        int base = fr * ORIG_R - WIDTH + c;
        float v0 = (base     >= 0 && base     < T_IN) ? xr[base]     : 0.f;
        float v1 = (base + 1 >= 0 && base + 1 < T_IN) ? xr[base + 1] : 0.f;
        float v2 = (base + 2 >= 0 && base + 2 < T_IN) ? xr[base + 2] : 0.f;
        float v3 = (base + 3 >= 0 && base + 3 < T_IN) ? xr[base + 3] : 0.f;
        unsigned short h0 = f2bf(v0), h1 = f2bf(v1), h2 = f2bf(v2), h3 = f2bf(v3);
        unsigned short l0 = f2bf(v0 - bf2f(h0)), l1 = f2bf(v1 - bf2f(h1));
        unsigned short l2 = f2bf(v2 - bf2f(h2)), l3 = f2bf(v3 - bf2f(h3));
        int tile = r >> 4, m = r & 15;
        int ks = c >> 5, qd = (c >> 3) & 3, j0 = c & 7;
        int off = ks * 512 + (qd * 16 + m) * 8 + j0;
        *(short4*)&Ah[tile][off] = make_short4(h0, h1, h2, h3);
        *(short4*)&Al[tile][off] = make_short4(l0, l1, l2, l3);
    }
    __syncthreads();

    int w    = threadIdx.x >> 6;
    int lane = threadIdx.x & 63;
    int l15  = lane & 15;
    int quad = lane >> 4;

    floatx4 acc00 = {0,0,0,0}, acc01 = {0,0,0,0};
    floatx4 acc10 = {0,0,0,0}, acc11 = {0,0,0,0};

    const unsigned short* b0h = kth + (w * 2    ) * 7680 + lane * 8;
    const unsigned short* b1h = kth + (w * 2 + 1) * 7680 + lane * 8;
    const unsigned short* b0l = ktl + (w * 2    ) * 7680 + lane * 8;
    const unsigned short* b1l = ktl + (w * 2 + 1) * 7680 + lane * 8;
    const unsigned short* a0h = &Ah[0][lane * 8];
    const unsigned short* a1h = &Ah[1][lane * 8];
    const unsigned short* a0l = &Al[0][lane * 8];
    const unsigned short* a1l = &Al[1][lane * 8];

#pragma unroll
    for (int ks = 0; ks < 15; ++ks) {
        int o = ks * 512;
        short8 kh0 = *(const short8*)(b0h + o);
        short8 kh1 = *(const short8*)(b1h + o);
        short8 kl0 = *(const short8*)(b0l + o);
        short8 kl1 = *(const short8*)(b1l + o);
        short8 ah0 = *(const short8*)(a0h + o);
        short8 al0 = *(const short8*)(a0l + o);
        short8 ah1 = *(const short8*)(a1h + o);
        short8 al1 = *(const short8*)(a1l + o);

        acc00 = __builtin_amdgcn_mfma_f32_16x16x32_bf16(ah0, kh0, acc00, 0, 0, 0);
        acc00 = __builtin_amdgcn_mfma_f32_16x16x32_bf16(ah0, kl0, acc00, 0, 0, 0);
        acc00 = __builtin_amdgcn_mfma_f32_16x16x32_bf16(al0, kh0, acc00, 0, 0, 0);
        acc01 = __builtin_amdgcn_mfma_f32_16x16x32_bf16(ah0, kh1, acc01, 0, 0, 0);
        acc01 = __builtin_amdgcn_mfma_f32_16x16x32_bf16(ah0, kl1, acc01, 0, 0, 0);
        acc01 = __builtin_amdgcn_mfma_f32_16x16x32_bf16(al0, kh1, acc01, 0, 0, 0);
        acc10 = __builtin_amdgcn_mfma_f32_16x16x32_bf16(ah1, kh0, acc10, 0, 0, 0);
        acc10 = __builtin_amdgcn_mfma_f32_16x16x32_bf16(ah1, kl0, acc10, 0, 0, 0);
        acc10 = __builtin_amdgcn_mfma_f32_16x16x32_bf16(al1, kh0, acc10, 0, 0, 0);
        acc11 = __builtin_amdgcn_mfma_f32_16x16x32_bf16(ah1, kh1, acc11, 0, 0, 0);
        acc11 = __builtin_amdgcn_mfma_f32_16x16x32_bf16(ah1, kl1, acc11, 0, 0, 0);
        acc11 = __builtin_amdgcn_mfma_f32_16x16x32_bf16(al1, kh1, acc11, 0, 0, 0);
    }

    // C/D layout: n = lane&15 (phase), m = quad*4 + reg (frame) -- verified R7/R8
    int obase = (batch * NB + band) * TB_OUT;
    int p0 = w * 32;
#pragma unroll
    for (int r = 0; r < 4; ++r) {
        int fr0 = f0 + quad * 4 + r;
        int fr1 = fr0 + 16;
        if (fr0 < NFRAMES) {
            out[obase + fr0 * NEW_R + p0 + l15]      = acc00[r];
            out[obase + fr0 * NEW_R + p0 + 16 + l15] = acc01[r];
        }
        if (fr1 < NFRAMES) {
            out[obase + fr1 * NEW_R + p0 + l15]      = acc10[r];
            out[obase + fr1 * NEW_R + p0 + 16 + l15] = acc11[r];
        }
    }
}

// ---------------- host ----------------
extern "C" void kernel_launch(void* const* d_in, const int* in_sizes, int n_in,
                              void* d_out, int out_size, void* d_ws, size_t ws_size,
                              hipStream_t stream) {
    const float*    x   = (const float*)d_in[0];
    float*          out = (float*)d_out;
    unsigned short* kth = (unsigned short*)((char*)d_ws + KTH_OFF);
    unsigned short* ktl = (unsigned short*)((char*)d_ws + KTL_OFF);
    float*          xlp = (float*)((char*)d_ws + XLP_OFF);

    ScanParams P;
    const double centers[NB] = {4000.0, 12000.0, 19025.0};
    const double Qs[NB]      = {0.5, 1.5, 19025.0 / 6050.0};
    for (int b = 0; b < NB; ++b) {
        double c  = centers[b], Q = Qs[b];
        double w0 = 2.0 * M_PI * c / 44100.0;
        double al = sin(w0) / (2.0 * Q);
        double a0 = 1.0 + al;
        P.b0[b] = (float)(al / a0);
        P.a1[b] = (float)(-2.0 * cos(w0) / a0);
        P.a2[b] = (float)((1.0 - al) / a0);
        P.w[b]  = 6.283185307179586f * (float)c;   // fl32(fl32(2pi)*c), validated
    }
    {
        double cut = 0.45 * 16000.0;
        double Q   = 0.7071067811865476;
        double w0  = 2.0 * M_PI * cut / 44100.0;
        double al  = sin(w0) / (2.0 * Q);
        double cs  = cos(w0);
        double a0  = 1.0 + al;
        P.lb0 = (float)(((1.0 - cs) / 2.0) / a0);
        P.lb1 = (float)((1.0 - cs) / a0);
        P.lb2 = P.lb0;
        P.la1 = (float)(-2.0 * cs / a0);
        P.la2 = (float)((1.0 - al) / a0);
    }

    // 1) frag-major bf16-split sinc tables
    kt_init_kernel<<<dim3((NEW_R * KP + 255) / 256), dim3(256), 0, stream>>>(kth, ktl);

    // 2) fused IIR cascade -> xlp (24 x 441000 f32), 147000 chunks, 128-thread blocks
    int nthreads = NSEQ * NCHUNK;                    // 147000
    scan_kernel<<<dim3((nthreads + 127) / 128), dim3(128), 0, stream>>>(x, xlp, P);

    // 3) MFMA polyphase resample -> out (8 x 3 x 160000)
    resample_mfma<<<dim3(NSEQ * MT2), dim3(320), 0, stream>>>(xlp, kth, ktl, out);
}

// Round 10
// 145.774 us; speedup vs baseline: 1.0105x; 1.0105x over previous
//
#include <hip/hip_runtime.h>
#include <math.h>

// ---------------- problem constants ----------------
#define SRATE   44100
#define T_IN    441000
#define BATCH   8
#define NB      3
#define NSEQ    (NB*BATCH)        // 24
#define TB_OUT  160000
#define NEW_R   160
#define ORIG_R  441
#define KW      475               // sinc taps
#define KP      480               // K padded to 15*32 for MFMA
#define WIDTH   17
#define NFRAMES 1000

// IIR chunking: 441000 = 6125 * 72 ; warmup 104 (residual proven invisible R8/R9).
// Span 176 = 44 quads. 147K threads = 9 waves/CU.
#define LCHUNK  72
#define NCHUNK  6125
#define WARM    104

// workspace layout
#define KTH_OFF 0                 // frag-major bf16-hi table: 160*480 ushort = 153.6 KB
#define KTL_OFF (256u<<10)        // bf16-lo table
#define XLP_OFF (1u<<20)          // xlp f32: 24*441000*4 = 42.3 MB

typedef __attribute__((ext_vector_type(4))) float floatx4;
typedef __attribute__((ext_vector_type(8))) short short8;

// bf16 helpers (RNE) — proven R7
__device__ inline unsigned short f2bf(float f) {
    union { float f; unsigned u; } v; v.f = f;
    unsigned u = v.u, r = (u >> 16) & 0xffffu, rem = u & 0xffffu;
    if (rem > 0x8000u || (rem == 0x8000u && (r & 1u))) r++;
    return (unsigned short)r;
}
__device__ inline float bf2f(unsigned short h) {
    union { unsigned u; float f; } v; v.u = ((unsigned)h) << 16; return v.f;
}

// frag-major flat index (proven R8): ktT[p][k], p = pblk*16+n, k = ks*32+qd*8+j
__device__ inline int fragB(int p, int k) {
    int pblk = p >> 4, n = p & 15;
    int ks = k >> 5, qd = (k >> 3) & 3, j = k & 7;
    return pblk * 7680 + ks * 512 + (qd * 16 + n) * 8 + j;
}

// ---------------- sinc table -> frag-major bf16-split (math proven R7/R8) ----------------
__global__ void kt_init_kernel(unsigned short* __restrict__ kth,
                               unsigned short* __restrict__ ktl) {
    int idx = blockIdx.x * blockDim.x + threadIdx.x;
    if (idx >= NEW_R * KP) return;
    int p = idx / KP, k = idx - p * KP;
    float v = 0.f;
    if (k < KW) {
        double t = (double)(k - WIDTH) * (158.4 / 441.0) - (double)p * 0.99;
        t = fmin(6.0, fmax(-6.0, t));
        float wc = __builtin_amdgcn_cosf((float)(t * (1.0 / 24.0)));
        double n = rint(t);
        float r2 = (float)((t - n) * 0.5);
        float sp = __builtin_amdgcn_sinf(r2 - floorf(r2));
        if (((long long)n) & 1) sp = -sp;
        float tp = (float)(t * M_PI);
        float snc = (t == 0.0) ? 1.f : sp / tp;
        v = snc * wc * wc * 0.3591836734693878f;
    }
    unsigned short h = f2bf(v);
    int flat = fragB(p, k);
    kth[flat] = h;
    ktl[flat] = f2bf(v - bf2f(h));
}

// ---------------- fused bandpass -> clip -> cos mix -> lowpass -> clip scan (f32) ----
// Heterodyne = XLA-f32 arithmetic (validated R5-R9 at bf16 floor).
// Prefetch: UNCONDITIONAL loads with clamped index (select-before-load), 3-stage
// a/b/t ring -> every quad loaded 2 iterations (~1400 cyc) before its use, so the
// compiler's vmcnt wait lands after compute instead of serializing each iteration.
struct ScanParams {
    float b0[NB], a1[NB], a2[NB], w[NB];
    float lb0, lb1, lb2, la1, la2;
};

__global__ __launch_bounds__(128) void scan_kernel(const float* __restrict__ x,
                                                   float* __restrict__ xlp,
                                                   ScanParams P) {
    int id = blockIdx.x * blockDim.x + threadIdx.x;
    if (id >= NSEQ * NCHUNK) return;
    int seq   = id / NCHUNK;
    int chunk = id - seq * NCHUNK;
    int band  = seq / BATCH;
    int batch = seq - band * BATCH;

    float b0f = (band == 0) ? P.b0[0] : (band == 1) ? P.b0[1] : P.b0[2];
    float a1f = (band == 0) ? P.a1[0] : (band == 1) ? P.a1[1] : P.a1[2];
    float a2f = (band == 0) ? P.a2[0] : (band == 1) ? P.a2[1] : P.a2[2];
    float wf  = (band == 0) ? P.w[0]  : (band == 1) ? P.w[1]  : P.w[2];
    float b2f = -b0f;
    float lb0 = P.lb0, lb1 = P.lb1, lb2 = P.lb2, la1 = P.la1, la2 = P.la2;

    const float*  xr   = x + batch * T_IN;
    float*        orow = xlp + seq * T_IN;
    const float4* xr4  = (const float4*)xr;

    int t0 = chunk * LCHUNK;          // multiple of 4
    int s0 = t0 - WARM; if (s0 < 0) s0 = 0;
    int e  = t0 + LCHUNK;
    int nq = (e - s0) >> 2;           // 44 (chunk 0: 18)
    int nqm1 = nq - 1;

    float bx1 = 0.f, bx2 = 0.f, by1 = 0.f, by2 = 0.f;
    float mx1 = 0.f, mx2 = 0.f, mz1 = 0.f, mz2 = 0.f;

    const float invsr  = 1.0f / 44100.0f;
    const float INV2PI = 0.15915494309189535f;
    const float PI2_A  = 6.28318548202514648f;
    const float PI2_B  = -1.7484556000744487e-7f;

    const float4* pp = xr4 + (s0 >> 2);
    float4 a0 = pp[0];
    float4 a1 = pp[1 < nqm1 ? 1 : nqm1];
    float4 a2 = pp[2 < nqm1 ? 2 : nqm1];
    float4 a3 = pp[3 < nqm1 ? 3 : nqm1];
    float4 b0 = pp[4 < nqm1 ? 4 : nqm1];
    float4 b1 = pp[5 < nqm1 ? 5 : nqm1];
    float4 b2 = pp[6 < nqm1 ? 6 : nqm1];
    float4 b3 = pp[7 < nqm1 ? 7 : nqm1];

    for (int iq = 0; iq < nq; iq += 4) {
        int pf = iq + 8;
        float4 t0v = pp[pf     < nqm1 ? pf     : nqm1];
        float4 t1v = pp[pf + 1 < nqm1 ? pf + 1 : nqm1];
        float4 t2v = pp[pf + 2 < nqm1 ? pf + 2 : nqm1];
        float4 t3v = pp[pf + 3 < nqm1 ? pf + 3 : nqm1];

#define STEP(XT, TI, OUT) {                                                   \
        float y  = b0f*(XT) + b2f*bx2 - a1f*by1 - a2f*by2;                    \
        bx2 = bx1; bx1 = (XT); by2 = by1; by1 = y;                            \
        float cy = fminf(fmaxf(y, -1.f), 1.f);                                \
        float tf = (float)(TI) * invsr;                                       \
        float X  = wf * tf;                                                   \
        float kk = __builtin_rintf(X * INV2PI);                               \
        float r  = fmaf(-kk, PI2_A, X);                                       \
        r        = fmaf(-kk, PI2_B, r);                                       \
        float cv = __builtin_amdgcn_cosf(r * INV2PI);                         \
        float m  = cy * cv;                                                   \
        float z  = lb0*m + lb1*mx1 + lb2*mx2 - la1*mz1 - la2*mz2;             \
        mx2 = mx1; mx1 = m; mz2 = mz1; mz1 = z;                               \
        OUT = fminf(fmaxf(z, -1.f), 1.f); }

#define QUAD(CV, QI) {                                                        \
        int s = s0 + ((iq + QI) << 2);                                        \
        float o0, o1, o2, o3;                                                 \
        STEP(CV.x, s,     o0)                                                 \
        STEP(CV.y, s + 1, o1)                                                 \
        STEP(CV.z, s + 2, o2)                                                 \
        STEP(CV.w, s + 3, o3)                                                 \
        if (s >= t0 && s < e)                                                 \
            ((float4*)orow)[s >> 2] = make_float4(o0, o1, o2, o3); }

        QUAD(a0, 0)
        QUAD(a1, 1)
        QUAD(a2, 2)
        QUAD(a3, 3)
#undef QUAD
#undef STEP
        a0 = b0; a1 = b1; a2 = b2; a3 = b3;
        b0 = t0v; b1 = t1v; b2 = t2v; b3 = t3v;
    }
}

// ---------------- MFMA resample (proven R8): out[f,p] = sum_k x[f*441+k-17]*kt[k][p] ----
#define MT2   32      // 32 blocks per sequence x 32 frames = 1024 >= 1000

__global__ __launch_bounds__(320) void resample_mfma(const float* __restrict__ xlp,
                                                     const unsigned short* __restrict__ kth,
                                                     const unsigned short* __restrict__ ktl,
                                                     float* __restrict__ out) {
    __shared__ unsigned short Ah[2][7680];
    __shared__ unsigned short Al[2][7680];

    int bid = blockIdx.x;
    int seq = bid / MT2;
    int mt  = bid - seq * MT2;
    int band  = seq / BATCH;
    int batch = seq - band * BATCH;
    int f0 = mt * 32;
    const float* xr = xlp + seq * T_IN;

    for (int i = threadIdx.x; i < 32 * 120; i += 320) {
        int r  = i / 120;
        int q  = i - r * 120;
        int c  = q * 4;
        int fr = f0 + r;
        int base = fr * ORIG_R - WIDTH + c;
        float v0 = (base     >= 0 && base     < T_IN) ? xr[base]     : 0.f;
        float v1 = (base + 1 >= 0 && base + 1 < T_IN) ? xr[base + 1] : 0.f;
        float v2 = (base + 2 >= 0 && base + 2 < T_IN) ? xr[base + 2] : 0.f;
        float v3 = (base + 3 >= 0 && base + 3 < T_IN) ? xr[base + 3] : 0.f;
        unsigned short h0 = f2bf(v0), h1 = f2bf(v1), h2 = f2bf(v2), h3 = f2bf(v3);
        unsigned short l0 = f2bf(v0 - bf2f(h0)), l1 = f2bf(v1 - bf2f(h1));
        unsigned short l2 = f2bf(v2 - bf2f(h2)), l3 = f2bf(v3 - bf2f(h3));
        int tile = r >> 4, m = r & 15;
        int ks = c >> 5, qd = (c >> 3) & 3, j0 = c & 7;
        int off = ks * 512 + (qd * 16 + m) * 8 + j0;
        *(short4*)&Ah[tile][off] = make_short4(h0, h1, h2, h3);
        *(short4*)&Al[tile][off] = make_short4(l0, l1, l2, l3);
    }
    __syncthreads();

    int w    = threadIdx.x >> 6;
    int lane = threadIdx.x & 63;
    int l15  = lane & 15;
    int quad = lane >> 4;

    floatx4 acc00 = {0,0,0,0}, acc01 = {0,0,0,0};
    floatx4 acc10 = {0,0,0,0}, acc11 = {0,0,0,0};

    const unsigned short* b0h = kth + (w * 2    ) * 7680 + lane * 8;
    const unsigned short* b1h = kth + (w * 2 + 1) * 7680 + lane * 8;
    const unsigned short* b0l = ktl + (w * 2    ) * 7680 + lane * 8;
    const unsigned short* b1l = ktl + (w * 2 + 1) * 7680 + lane * 8;
    const unsigned short* a0h = &Ah[0][lane * 8];
    const unsigned short* a1h = &Ah[1][lane * 8];
    const unsigned short* a0l = &Al[0][lane * 8];
    const unsigned short* a1l = &Al[1][lane * 8];

#pragma unroll
    for (int ks = 0; ks < 15; ++ks) {
        int o = ks * 512;
        short8 kh0 = *(const short8*)(b0h + o);
        short8 kh1 = *(const short8*)(b1h + o);
        short8 kl0 = *(const short8*)(b0l + o);
        short8 kl1 = *(const short8*)(b1l + o);
        short8 ah0 = *(const short8*)(a0h + o);
        short8 al0 = *(const short8*)(a0l + o);
        short8 ah1 = *(const short8*)(a1h + o);
        short8 al1 = *(const short8*)(a1l + o);

        acc00 = __builtin_amdgcn_mfma_f32_16x16x32_bf16(ah0, kh0, acc00, 0, 0, 0);
        acc00 = __builtin_amdgcn_mfma_f32_16x16x32_bf16(ah0, kl0, acc00, 0, 0, 0);
        acc00 = __builtin_amdgcn_mfma_f32_16x16x32_bf16(al0, kh0, acc00, 0, 0, 0);
        acc01 = __builtin_amdgcn_mfma_f32_16x16x32_bf16(ah0, kh1, acc01, 0, 0, 0);
        acc01 = __builtin_amdgcn_mfma_f32_16x16x32_bf16(ah0, kl1, acc01, 0, 0, 0);
        acc01 = __builtin_amdgcn_mfma_f32_16x16x32_bf16(al0, kh1, acc01, 0, 0, 0);
        acc10 = __builtin_amdgcn_mfma_f32_16x16x32_bf16(ah1, kh0, acc10, 0, 0, 0);
        acc10 = __builtin_amdgcn_mfma_f32_16x16x32_bf16(ah1, kl0, acc10, 0, 0, 0);
        acc10 = __builtin_amdgcn_mfma_f32_16x16x32_bf16(al1, kh0, acc10, 0, 0, 0);
        acc11 = __builtin_amdgcn_mfma_f32_16x16x32_bf16(ah1, kh1, acc11, 0, 0, 0);
        acc11 = __builtin_amdgcn_mfma_f32_16x16x32_bf16(ah1, kl1, acc11, 0, 0, 0);
        acc11 = __builtin_amdgcn_mfma_f32_16x16x32_bf16(al1, kh1, acc11, 0, 0, 0);
    }

    // C/D layout: n = lane&15 (phase), m = quad*4 + reg (frame) -- verified R7/R8
    int obase = (batch * NB + band) * TB_OUT;
    int p0 = w * 32;
#pragma unroll
    for (int r = 0; r < 4; ++r) {
        int fr0 = f0 + quad * 4 + r;
        int fr1 = fr0 + 16;
        if (fr0 < NFRAMES) {
            out[obase + fr0 * NEW_R + p0 + l15]      = acc00[r];
            out[obase + fr0 * NEW_R + p0 + 16 + l15] = acc01[r];
        }
        if (fr1 < NFRAMES) {
            out[obase + fr1 * NEW_R + p0 + l15]      = acc10[r];
            out[obase + fr1 * NEW_R + p0 + 16 + l15] = acc11[r];
        }
    }
}

// ---------------- host ----------------
extern "C" void kernel_launch(void* const* d_in, const int* in_sizes, int n_in,
                              void* d_out, int out_size, void* d_ws, size_t ws_size,
                              hipStream_t stream) {
    const float*    x   = (const float*)d_in[0];
    float*          out = (float*)d_out;
    unsigned short* kth = (unsigned short*)((char*)d_ws + KTH_OFF);
    unsigned short* ktl = (unsigned short*)((char*)d_ws + KTL_OFF);
    float*          xlp = (float*)((char*)d_ws + XLP_OFF);

    ScanParams P;
    const double centers[NB] = {4000.0, 12000.0, 19025.0};
    const double Qs[NB]      = {0.5, 1.5, 19025.0 / 6050.0};
    for (int b = 0; b < NB; ++b) {
        double c  = centers[b], Q = Qs[b];
        double w0 = 2.0 * M_PI * c / 44100.0;
        double al = sin(w0) / (2.0 * Q);
        double a0 = 1.0 + al;
        P.b0[b] = (float)(al / a0);
        P.a1[b] = (float)(-2.0 * cos(w0) / a0);
        P.a2[b] = (float)((1.0 - al) / a0);
        P.w[b]  = 6.283185307179586f * (float)c;   // fl32(fl32(2pi)*c), validated
    }
    {
        double cut = 0.45 * 16000.0;
        double Q   = 0.7071067811865476;
        double w0  = 2.0 * M_PI * cut / 44100.0;
        double al  = sin(w0) / (2.0 * Q);
        double cs  = cos(w0);
        double a0  = 1.0 + al;
        P.lb0 = (float)(((1.0 - cs) / 2.0) / a0);
        P.lb1 = (float)((1.0 - cs) / a0);
        P.lb2 = P.lb0;
        P.la1 = (float)(-2.0 * cs / a0);
        P.la2 = (float)((1.0 - al) / a0);
    }

    // 1) frag-major bf16-split sinc tables
    kt_init_kernel<<<dim3((NEW_R * KP + 255) / 256), dim3(256), 0, stream>>>(kth, ktl);

    // 2) fused IIR cascade -> xlp (24 x 441000 f32)
    int nthreads = NSEQ * NCHUNK;                    // 147000
    scan_kernel<<<dim3((nthreads + 127) / 128), dim3(128), 0, stream>>>(x, xlp, P);

    // 3) MFMA polyphase resample -> out (8 x 3 x 160000)
    resample_mfma<<<dim3(NSEQ * MT2), dim3(320), 0, stream>>>(xlp, kth, ktl, out);
}

// Round 11
// 140.079 us; speedup vs baseline: 1.0516x; 1.0406x over previous
//
#include <hip/hip_runtime.h>
#include <math.h>

// ---------------- problem constants ----------------
#define SRATE   44100
#define T_IN    441000
#define BATCH   8
#define NB      3
#define NSEQ    (NB*BATCH)        // 24
#define TB_OUT  160000
#define NEW_R   160
#define ORIG_R  441
#define KW      475               // sinc taps
#define KP      480               // K padded to 15*32 for MFMA
#define WIDTH   17
#define NFRAMES 1000

// IIR chunking: 441000 = 6125 * 72 ; warmup 104 (residual proven invisible R8-R10).
#define LCHUNK  72
#define NCHUNK  6125
#define WARM    104
#define CPB     128               // chunks (= threads) per scan block
#define BPS     48                // blocks per sequence: 48*128 = 6144 >= 6125
#define SPAN4   (CPB*18 + 26)     // (CPB*72 + 104)/4 = 2330 float4s = 37,280 B LDS

// workspace layout
#define KTH_OFF 0                 // frag-major bf16-hi table: 160*480 ushort = 153.6 KB
#define KTL_OFF (256u<<10)        // bf16-lo table
#define XLP_OFF (1u<<20)          // xlp f32: 24*441000*4 = 42.3 MB

typedef __attribute__((ext_vector_type(4))) float floatx4;
typedef __attribute__((ext_vector_type(8))) short short8;

// bf16 helpers (RNE) — proven R7
__device__ inline unsigned short f2bf(float f) {
    union { float f; unsigned u; } v; v.f = f;
    unsigned u = v.u, r = (u >> 16) & 0xffffu, rem = u & 0xffffu;
    if (rem > 0x8000u || (rem == 0x8000u && (r & 1u))) r++;
    return (unsigned short)r;
}
__device__ inline float bf2f(unsigned short h) {
    union { unsigned u; float f; } v; v.u = ((unsigned)h) << 16; return v.f;
}

// frag-major flat index (proven R8)
__device__ inline int fragB(int p, int k) {
    int pblk = p >> 4, n = p & 15;
    int ks = k >> 5, qd = (k >> 3) & 3, j = k & 7;
    return pblk * 7680 + ks * 512 + (qd * 16 + n) * 8 + j;
}

// ---------------- sinc table -> frag-major bf16-split (proven R7/R8) ----------------
__global__ void kt_init_kernel(unsigned short* __restrict__ kth,
                               unsigned short* __restrict__ ktl) {
    int idx = blockIdx.x * blockDim.x + threadIdx.x;
    if (idx >= NEW_R * KP) return;
    int p = idx / KP, k = idx - p * KP;
    float v = 0.f;
    if (k < KW) {
        double t = (double)(k - WIDTH) * (158.4 / 441.0) - (double)p * 0.99;
        t = fmin(6.0, fmax(-6.0, t));
        float wc = __builtin_amdgcn_cosf((float)(t * (1.0 / 24.0)));
        double n = rint(t);
        float r2 = (float)((t - n) * 0.5);
        float sp = __builtin_amdgcn_sinf(r2 - floorf(r2));
        if (((long long)n) & 1) sp = -sp;
        float tp = (float)(t * M_PI);
        float snc = (t == 0.0) ? 1.f : sp / tp;
        v = snc * wc * wc * 0.3591836734693878f;
    }
    unsigned short h = f2bf(v);
    int flat = fragB(p, k);
    kth[flat] = h;
    ktl[flat] = f2bf(v - bf2f(h));
}

// ---------------- fused bandpass -> clip -> cos mix -> lowpass -> clip scan (f32) ----
// Heterodyne = XLA-f32 arithmetic (validated R5-R10 at bf16 floor).
// NEW (R11): block stages its contiguous 9320-float span into LDS with perfectly
// coalesced float4 loads (the R10 counters showed the scatter pattern capped HBM at
// ~2.5 TB/s); lanes then read their chunk windows from LDS. Zero-filled head for
// chunk 0 is semantics-preserving (zero input keeps zero state).
struct ScanParams {
    float b0[NB], a1[NB], a2[NB], w[NB];
    float lb0, lb1, lb2, la1, la2;
};

__global__ __launch_bounds__(128) void scan_kernel(const float* __restrict__ x,
                                                   float* __restrict__ xlp,
                                                   ScanParams P) {
    __shared__ float4 ls[SPAN4];

    int bid = blockIdx.x;
    int seq = bid / BPS;
    int blk = bid - seq * BPS;
    int band  = seq / BATCH;
    int batch = seq - band * BATCH;

    float b0f = (band == 0) ? P.b0[0] : (band == 1) ? P.b0[1] : P.b0[2];
    float a1f = (band == 0) ? P.a1[0] : (band == 1) ? P.a1[1] : P.a1[2];
    float a2f = (band == 0) ? P.a2[0] : (band == 1) ? P.a2[1] : P.a2[2];
    float wf  = (band == 0) ? P.w[0]  : (band == 1) ? P.w[1]  : P.w[2];
    float b2f = -b0f;
    float lb0 = P.lb0, lb1 = P.lb1, lb2 = P.lb2, la1 = P.la1, la2 = P.la2;

    const float4* xr4   = (const float4*)(x + batch * T_IN);
    float*        orow  = xlp + seq * T_IN;

    // ---- stage contiguous span [cbase*72 - 104, (cbase+CPB)*72) into LDS ----
    int cbase  = blk * CPB;
    int g4base = (cbase * 18) - 26;           // (cbase*72 - 104)/4, may be negative
    const float4 zero = make_float4(0.f, 0.f, 0.f, 0.f);
    for (int i = threadIdx.x; i < SPAN4; i += 128) {
        int g4 = g4base + i;
        ls[i] = (g4 >= 0 && g4 < T_IN / 4) ? xr4[g4] : zero;
    }
    __syncthreads();

    int cin   = threadIdx.x;
    int chunk = cbase + cin;
    bool valid = chunk < NCHUNK;
    int t0 = chunk * LCHUNK;

    float bx1 = 0.f, bx2 = 0.f, by1 = 0.f, by2 = 0.f;
    float mx1 = 0.f, mx2 = 0.f, mz1 = 0.f, mz2 = 0.f;

    const float invsr  = 1.0f / 44100.0f;
    const float INV2PI = 0.15915494309189535f;
    const float PI2_A  = 6.28318548202514648f;
    const float PI2_B  = -1.7484556000744487e-7f;

    int b4 = cin * 18;                        // lane's window start (float4 units)
    float4 cur = ls[b4];

#define STEP(XT, TI, OUT) {                                                   \
        float y  = b0f*(XT) + b2f*bx2 - a1f*by1 - a2f*by2;                    \
        bx2 = bx1; bx1 = (XT); by2 = by1; by1 = y;                            \
        float cy = fminf(fmaxf(y, -1.f), 1.f);                                \
        float tf = (float)(TI) * invsr;                                       \
        float X  = wf * tf;                                                   \
        float kk = __builtin_rintf(X * INV2PI);                               \
        float r  = fmaf(-kk, PI2_A, X);                                       \
        r        = fmaf(-kk, PI2_B, r);                                       \
        float cv = __builtin_amdgcn_cosf(r * INV2PI);                         \
        float m  = cy * cv;                                                   \
        float z  = lb0*m + lb1*mx1 + lb2*mx2 - la1*mz1 - la2*mz2;             \
        mx2 = mx1; mx1 = m; mz2 = mz1; mz1 = z;                               \
        OUT = fminf(fmaxf(z, -1.f), 1.f); }

    // warm-up: 26 quads (104 samples), no store
    for (int iq = 0; iq < 26; ++iq) {
        float4 nxt = ls[b4 + iq + 1];
        int s = t0 - WARM + (iq << 2);
        float o0, o1, o2, o3;
        STEP(cur.x, s,     o0)
        STEP(cur.y, s + 1, o1)
        STEP(cur.z, s + 2, o2)
        STEP(cur.w, s + 3, o3)
        (void)o0; (void)o1; (void)o2; (void)o3;
        cur = nxt;
    }
    // output: 18 quads (72 samples)
    for (int iq = 26; iq < 44; ++iq) {
        int nx = iq + 1 < 44 ? iq + 1 : 43;
        float4 nxt = ls[b4 + nx];
        int s = t0 - WARM + (iq << 2);
        float o0, o1, o2, o3;
        STEP(cur.x, s,     o0)
        STEP(cur.y, s + 1, o1)
        STEP(cur.z, s + 2, o2)
        STEP(cur.w, s + 3, o3)
        if (valid) ((float4*)orow)[(t0 >> 2) + (iq - 26)] = make_float4(o0, o1, o2, o3);
        cur = nxt;
    }
#undef STEP
}

// ---------------- MFMA resample (proven R8): out[f,p] = sum_k x[f*441+k-17]*kt[k][p] ----
#define MT2   32      // 32 blocks per sequence x 32 frames = 1024 >= 1000

__global__ __launch_bounds__(320) void resample_mfma(const float* __restrict__ xlp,
                                                     const unsigned short* __restrict__ kth,
                                                     const unsigned short* __restrict__ ktl,
                                                     float* __restrict__ out) {
    __shared__ unsigned short Ah[2][7680];
    __shared__ unsigned short Al[2][7680];

    int bid = blockIdx.x;
    int seq = bid / MT2;
    int mt  = bid - seq * MT2;
    int band  = seq / BATCH;
    int batch = seq - band * BATCH;
    int f0 = mt * 32;
    const float* xr = xlp + seq * T_IN;

    for (int i = threadIdx.x; i < 32 * 120; i += 320) {
        int r  = i / 120;
        int q  = i - r * 120;
        int c  = q * 4;
        int fr = f0 + r;
        int base = fr * ORIG_R - WIDTH + c;
        float v0 = (base     >= 0 && base     < T_IN) ? xr[base]     : 0.f;
        float v1 = (base + 1 >= 0 && base + 1 < T_IN) ? xr[base + 1] : 0.f;
        float v2 = (base + 2 >= 0 && base + 2 < T_IN) ? xr[base + 2] : 0.f;
        float v3 = (base + 3 >= 0 && base + 3 < T_IN) ? xr[base + 3] : 0.f;
        unsigned short h0 = f2bf(v0), h1 = f2bf(v1), h2 = f2bf(v2), h3 = f2bf(v3);
        unsigned short l0 = f2bf(v0 - bf2f(h0)), l1 = f2bf(v1 - bf2f(h1));
        unsigned short l2 = f2bf(v2 - bf2f(h2)), l3 = f2bf(v3 - bf2f(h3));
        int tile = r >> 4, m = r & 15;
        int ks = c >> 5, qd = (c >> 3) & 3, j0 = c & 7;
        int off = ks * 512 + (qd * 16 + m) * 8 + j0;
        *(short4*)&Ah[tile][off] = make_short4(h0, h1, h2, h3);
        *(short4*)&Al[tile][off] = make_short4(l0, l1, l2, l3);
    }
    __syncthreads();

    int w    = threadIdx.x >> 6;
    int lane = threadIdx.x & 63;
    int l15  = lane & 15;
    int quad = lane >> 4;

    floatx4 acc00 = {0,0,0,0}, acc01 = {0,0,0,0};
    floatx4 acc10 = {0,0,0,0}, acc11 = {0,0,0,0};

    const unsigned short* b0h = kth + (w * 2    ) * 7680 + lane * 8;
    const unsigned short* b1h = kth + (w * 2 + 1) * 7680 + lane * 8;
    const unsigned short* b0l = ktl + (w * 2    ) * 7680 + lane * 8;
    const unsigned short* b1l = ktl + (w * 2 + 1) * 7680 + lane * 8;
    const unsigned short* a0h = &Ah[0][lane * 8];
    const unsigned short* a1h = &Ah[1][lane * 8];
    const unsigned short* a0l = &Al[0][lane * 8];
    const unsigned short* a1l = &Al[1][lane * 8];

#pragma unroll
    for (int ks = 0; ks < 15; ++ks) {
        int o = ks * 512;
        short8 kh0 = *(const short8*)(b0h + o);
        short8 kh1 = *(const short8*)(b1h + o);
        short8 kl0 = *(const short8*)(b0l + o);
        short8 kl1 = *(const short8*)(b1l + o);
        short8 ah0 = *(const short8*)(a0h + o);
        short8 al0 = *(const short8*)(a0l + o);
        short8 ah1 = *(const short8*)(a1h + o);
        short8 al1 = *(const short8*)(a1l + o);

        acc00 = __builtin_amdgcn_mfma_f32_16x16x32_bf16(ah0, kh0, acc00, 0, 0, 0);
        acc00 = __builtin_amdgcn_mfma_f32_16x16x32_bf16(ah0, kl0, acc00, 0, 0, 0);
        acc00 = __builtin_amdgcn_mfma_f32_16x16x32_bf16(al0, kh0, acc00, 0, 0, 0);
        acc01 = __builtin_amdgcn_mfma_f32_16x16x32_bf16(ah0, kh1, acc01, 0, 0, 0);
        acc01 = __builtin_amdgcn_mfma_f32_16x16x32_bf16(ah0, kl1, acc01, 0, 0, 0);
        acc01 = __builtin_amdgcn_mfma_f32_16x16x32_bf16(al0, kh1, acc01, 0, 0, 0);
        acc10 = __builtin_amdgcn_mfma_f32_16x16x32_bf16(ah1, kh0, acc10, 0, 0, 0);
        acc10 = __builtin_amdgcn_mfma_f32_16x16x32_bf16(ah1, kl0, acc10, 0, 0, 0);
        acc10 = __builtin_amdgcn_mfma_f32_16x16x32_bf16(al1, kh0, acc10, 0, 0, 0);
        acc11 = __builtin_amdgcn_mfma_f32_16x16x32_bf16(ah1, kh1, acc11, 0, 0, 0);
        acc11 = __builtin_amdgcn_mfma_f32_16x16x32_bf16(ah1, kl1, acc11, 0, 0, 0);
        acc11 = __builtin_amdgcn_mfma_f32_16x16x32_bf16(al1, kh1, acc11, 0, 0, 0);
    }

    // C/D layout: n = lane&15 (phase), m = quad*4 + reg (frame) -- verified R7/R8
    int obase = (batch * NB + band) * TB_OUT;
    int p0 = w * 32;
#pragma unroll
    for (int r = 0; r < 4; ++r) {
        int fr0 = f0 + quad * 4 + r;
        int fr1 = fr0 + 16;
        if (fr0 < NFRAMES) {
            out[obase + fr0 * NEW_R + p0 + l15]      = acc00[r];
            out[obase + fr0 * NEW_R + p0 + 16 + l15] = acc01[r];
        }
        if (fr1 < NFRAMES) {
            out[obase + fr1 * NEW_R + p0 + l15]      = acc10[r];
            out[obase + fr1 * NEW_R + p0 + 16 + l15] = acc11[r];
        }
    }
}

// ---------------- host ----------------
extern "C" void kernel_launch(void* const* d_in, const int* in_sizes, int n_in,
                              void* d_out, int out_size, void* d_ws, size_t ws_size,
                              hipStream_t stream) {
    const float*    x   = (const float*)d_in[0];
    float*          out = (float*)d_out;
    unsigned short* kth = (unsigned short*)((char*)d_ws + KTH_OFF);
    unsigned short* ktl = (unsigned short*)((char*)d_ws + KTL_OFF);
    float*          xlp = (float*)((char*)d_ws + XLP_OFF);

    ScanParams P;
    const double centers[NB] = {4000.0, 12000.0, 19025.0};
    const double Qs[NB]      = {0.5, 1.5, 19025.0 / 6050.0};
    for (int b = 0; b < NB; ++b) {
        double c  = centers[b], Q = Qs[b];
        double w0 = 2.0 * M_PI * c / 44100.0;
        double al = sin(w0) / (2.0 * Q);
        double a0 = 1.0 + al;
        P.b0[b] = (float)(al / a0);
        P.a1[b] = (float)(-2.0 * cos(w0) / a0);
        P.a2[b] = (float)((1.0 - al) / a0);
        P.w[b]  = 6.283185307179586f * (float)c;   // fl32(fl32(2pi)*c), validated
    }
    {
        double cut = 0.45 * 16000.0;
        double Q   = 0.7071067811865476;
        double w0  = 2.0 * M_PI * cut / 44100.0;
        double al  = sin(w0) / (2.0 * Q);
        double cs  = cos(w0);
        double a0  = 1.0 + al;
        P.lb0 = (float)(((1.0 - cs) / 2.0) / a0);
        P.lb1 = (float)((1.0 - cs) / a0);
        P.lb2 = P.lb0;
        P.la1 = (float)(-2.0 * cs / a0);
        P.la2 = (float)((1.0 - al) / a0);
    }

    // 1) frag-major bf16-split sinc tables
    kt_init_kernel<<<dim3((NEW_R * KP + 255) / 256), dim3(256), 0, stream>>>(kth, ktl);

    // 2) fused IIR cascade -> xlp (24 x 441000 f32), LDS-staged coalesced reads
    scan_kernel<<<dim3(NSEQ * BPS), dim3(CPB), 0, stream>>>(x, xlp, P);

    // 3) MFMA polyphase resample -> out (8 x 3 x 160000)
    resample_mfma<<<dim3(NSEQ * MT2), dim3(320), 0, stream>>>(xlp, kth, ktl, out);
}